// Round 4
// baseline (507.369 us; speedup 1.0000x reference)
//
#include <hip/hip_runtime.h>
#include <hip/hip_bf16.h>
#include <math.h>

typedef __hip_bfloat16 bf16;
typedef __bf16 bf16x8 __attribute__((ext_vector_type(8)));
typedef float f32x4 __attribute__((ext_vector_type(4)));

static constexpr int  B_  = 4, S_ = 2048, H_ = 1024;
static constexpr long BSH = (long)B_ * S_ * H_;   // 8,388,608
static constexpr long SH  = (long)S_ * H_;        // 2,097,152
static constexpr long SS  = (long)S_ * S_;        // 4,194,304
static constexpr long HH  = (long)H_ * H_;        // 1,048,576

// async global->LDS, 16B per lane; LDS dest is wave-uniform base + lane*16
#define GLOAD_LDS16(gp, lp)                                                          \
  __builtin_amdgcn_global_load_lds((__attribute__((address_space(1))) void*)(gp),    \
                                   (__attribute__((address_space(3))) void*)(lp),    \
                                   16, 0, 0)

// raw barrier (does NOT drain vmcnt) + compiler memory fence
#define BARRIER() do { __builtin_amdgcn_s_barrier(); asm volatile("" ::: "memory"); } while (0)
// barrier, then wait own ds_reads, then pin scheduler (rule 18)
#define PHASE_GATE() do { __builtin_amdgcn_s_barrier();                              \
  asm volatile("s_waitcnt lgkmcnt(0)" ::: "memory");                                 \
  __builtin_amdgcn_sched_barrier(0); } while (0)

template <int N> __device__ __forceinline__ void waitcnt_vm() {
  if constexpr (N == 0)      asm volatile("s_waitcnt vmcnt(0)" ::: "memory");
  else if constexpr (N == 3) asm volatile("s_waitcnt vmcnt(3)" ::: "memory");
  else if constexpr (N == 4) asm volatile("s_waitcnt vmcnt(4)" ::: "memory");
  else if constexpr (N == 6) asm volatile("s_waitcnt vmcnt(6)" ::: "memory");
  else if constexpr (N == 8) asm volatile("s_waitcnt vmcnt(8)" ::: "memory");
}

__device__ __forceinline__ float wave_reduce_sum(float v) {
#pragma unroll
  for (int o = 32; o; o >>= 1) v += __shfl_xor(v, o, 64);
  return v;
}
__device__ __forceinline__ float bf16r(float v) {
  return __bfloat162float(__float2bfloat16(v));
}

// -------- prep: weights fp32->bf16 (blocks 0..4095) + PE-add (blocks 4096..20479)
__global__ void prep_kernel(const float* __restrict__ Wq, const float* __restrict__ Wk,
                            const float* __restrict__ Wv, const float* __restrict__ Wo,
                            bf16* __restrict__ wdst,
                            const float* __restrict__ x, bf16* __restrict__ xpb) {
  const int bx  = blockIdx.x;
  const int tid = threadIdx.x;
  if (bx < 4096) {                       // ---- weight conversion, H*H/4 per weight
    const int w = bx >> 10;
    const float* src = (w == 0) ? Wq : (w == 1) ? Wk : (w == 2) ? Wv : Wo;
    bf16* d = wdst + (long)w * HH;
    const int idx = ((bx & 1023) << 8) + tid;
    const float4 f = ((const float4*)src)[idx];
    d[idx * 4 + 0] = __float2bfloat16(f.x);
    d[idx * 4 + 1] = __float2bfloat16(f.y);
    d[idx * 4 + 2] = __float2bfloat16(f.z);
    d[idx * 4 + 3] = __float2bfloat16(f.w);
  } else {                               // ---- xpb = bf16(x + pe), pair-indexed
    const long idx = (((long)(bx - 4096)) << 8) + tid;     // over B*S*(H/2)
    const int  i   = (int)(idx & (H_ / 2 - 1));
    const long bs  = idx >> 9;
    const int  s   = (int)(bs & (S_ - 1));
    const float div = __expf((float)(2 * i) * (-9.210340371976184f / (float)H_));
    const float ang = (float)s * div;
    const float2 xv = ((const float2*)x)[idx];
    xpb[idx * 2 + 0] = __float2bfloat16(xv.x + sinf(ang));
    xpb[idx * 2 + 1] = __float2bfloat16(xv.y + cosf(ang));
  }
}

// -------- NT GEMM, BM x 256 tile, BK=32, 512 thr (2x4 waves, per-wave BM/2 x 64) -
// m201-style phase schedule: per phase {stage-piece + ds_reads -> s_barrier ->
// lgkmcnt(0)+sched_barrier -> setprio(1) MFMA setprio(0) -> s_barrier}; 2 phases
// per K-tile; ring-4 LDS, prefetch distance 3; vmcnt counted ONCE per tile in the
// last phase (steady 2*LPT, epilogue LPT -> 0)  [T3+T4+T5].  Read-side XOR swizzle
// with inverse-permuted global source, linear gload_lds dest (conflicts == 0).
// Sync ledger: vmcnt-wait for tile kt+1 sits BEFORE phase-1's barrier of tile kt,
// so every wave's wait precedes the barrier that precedes kt+1's ds_reads.
// C[M,N] = A[M,K] * B[N,K]^T, A/B bf16 K-contiguous packed (ld == K).
// MODE 0: Cb = bf16(acc + biasz[col])                       (QKV, z picks bias)
// MODE 1: Cb = bf16(exp(clamp(acc/32 + pos_bias, mask)))    (unnormalized E)
// MODE 2: Cb = bf16(acc * inv_sum[z*S+row])                 (context, normalized)
// MODE 3: Cf = acc + bias0[col] + xres[m,n]          (fp32) (out proj + residual)
template <int MODE, int BM>
__global__ __launch_bounds__(512, 2)
void gemm_nt(const bf16* __restrict__ A, long strideA,
             const bf16* __restrict__ Bm, long strideB,
             bf16* __restrict__ Cb, float* __restrict__ Cf, long sC,
             int M, int N, int K,
             const float* __restrict__ bias0,
             const float* __restrict__ bias1,
             const float* __restrict__ bias2,
             const float* __restrict__ pos_bias,
             const int* __restrict__ mask,
             const float* __restrict__ xres,
             const float* __restrict__ inv_sum) {
  constexpr int BN = 256, BK = 32;
  constexpr int MR    = BM / 32;               // m-frags per wave: 8 (BM=256) / 4
  constexpr int MR2   = MR / 2;                // per phase: 4 / 2
  constexpr int LPT_A = BM / 128;              // A gloads/thread/tile: 2 / 1
  constexpr int LPT   = LPT_A + 2;             // total gloads/thread/tile: 4 / 3
  constexpr int WVM   = 2 * LPT;               // steady vmcnt: 8 / 6

  __shared__ bf16 sAb[4][BM * BK];             // 4 x 16|8 KB
  __shared__ bf16 sBb[4][BN * BK];             // 4 x 16 KB

  const int t    = threadIdx.x;
  const int lane = t & 63;
  const int wave = t >> 6;
  const int wm   = wave >> 2;                  // 0..1  (m half)
  const int wn   = wave & 3;                   // 0..3  (n quarter)
  const int z    = blockIdx.z;
  const int m0   = blockIdx.x * BM;
  const int n0   = blockIdx.y * BN;

  const bf16* Ab = A  + (long)z * strideA;
  const bf16* Bb = Bm + (long)z * strideB;

  // staging: slot s -> row s>>2, 16B-pos p = s&3; LDS dest linear (gload_lds);
  // global source column-slot = p ^ ((row>>1)&3)  == inverse of read swizzle
  const int rS  = t >> 2, pS = t & 3;
  const int swS = (rS >> 1) & 3;               // same for rS and rS+128
  const bf16* gA0 = Ab + (long)(m0 + rS)       * K + (pS ^ swS) * 8;
  const bf16* gA1 = Ab + (long)(m0 + rS + 128) * K + (pS ^ swS) * 8;  // BM==256 only
  const bf16* gB0 = Bb + (long)(n0 + rS)       * K + (pS ^ swS) * 8;
  const bf16* gB1 = Bb + (long)(n0 + rS + 128) * K + (pS ^ swS) * 8;

  auto stageA = [&](int tile) {
    const int buf = tile & 3, k0 = tile * BK;
    GLOAD_LDS16(gA0 + k0, &sAb[buf][t * 8]);
    if constexpr (BM == 256) GLOAD_LDS16(gA1 + k0, &sAb[buf][(t + 512) * 8]);
  };
  auto stageB = [&](int tile) {
    const int buf = tile & 3, k0 = tile * BK;
    GLOAD_LDS16(gB0 + k0, &sBb[buf][t * 8]);
    GLOAD_LDS16(gB1 + k0, &sBb[buf][(t + 512) * 8]);
  };

  // fragment read addressing: row*64B + ((kslot*16) ^ (row bits[1:2] << 4));
  // frag base rows are multiples of 16, so swizzle depends only on fr.
  const int fr  = lane & 15;
  const int cqs = ((lane >> 4) << 4) ^ (((fr >> 1) & 3) << 4);

  f32x4 acc[MR][4] = {};

  const int nkt = K / BK;                      // 32 or 64
  stageA(0); stageB(0);
  stageA(1); stageB(1);
  stageA(2); stageB(2);                        // 3 tiles in flight
  waitcnt_vm<WVM>();                           // tile 0 landed (per-wave)
  BARRIER();                                   // all waves confirmed

  for (int kt = 0; kt < nkt; ++kt) {
    const char* bA = (const char*)&sAb[kt & 3][0];
    const char* bB = (const char*)&sBb[kt & 3][0];
    const bool  st = (kt + 3 < nkt);

    // ---- phase 0: stage A(kt+3) | read B frags + A frags [0,MR2) | gate | MFMA
    if (st) stageA(kt + 3);
    bf16x8 bfv[4], af[MR2];
#pragma unroll
    for (int j = 0; j < 4; ++j)
      bfv[j] = *(const bf16x8*)(bB + (wn * 64 + j * 16 + fr) * 64 + cqs);
#pragma unroll
    for (int i = 0; i < MR2; ++i)
      af[i] = *(const bf16x8*)(bA + (wm * (BM / 2) + i * 16 + fr) * 64 + cqs);
    PHASE_GATE();
    __builtin_amdgcn_s_setprio(1);
#pragma unroll
    for (int i = 0; i < MR2; ++i)
#pragma unroll
      for (int j = 0; j < 4; ++j)
        acc[i][j] = __builtin_amdgcn_mfma_f32_16x16x32_bf16(af[i], bfv[j], acc[i][j], 0, 0, 0);
    __builtin_amdgcn_s_setprio(0);
    BARRIER();

    // ---- phase 1: stage B(kt+3) | read A frags [MR2,MR) | vmcnt(kt+1) | gate | MFMA
    if (st) stageB(kt + 3);
    bf16x8 af2[MR2];
#pragma unroll
    for (int i = 0; i < MR2; ++i)
      af2[i] = *(const bf16x8*)(bA + (wm * (BM / 2) + (MR2 + i) * 16 + fr) * 64 + cqs);
    if (kt < nkt - 3)       waitcnt_vm<WVM>();      // tile kt+1 landed; 2 in flight
    else if (kt == nkt - 3) waitcnt_vm<WVM / 2>();  // only kt+2 in flight
    else if (kt == nkt - 2) waitcnt_vm<0>();        // last tile landed
    PHASE_GATE();
    __builtin_amdgcn_s_setprio(1);
#pragma unroll
    for (int i = 0; i < MR2; ++i)
#pragma unroll
      for (int j = 0; j < 4; ++j)
        acc[MR2 + i][j] =
            __builtin_amdgcn_mfma_f32_16x16x32_bf16(af2[i], bfv[j], acc[MR2 + i][j], 0, 0, 0);
    __builtin_amdgcn_s_setprio(0);
    BARRIER();
  }

  const float* biasz = (MODE == 0) ? ((z == 0) ? bias0 : (z == 1) ? bias1 : bias2) : bias0;

  // C/D layout (verified m89/m91): col = lane&15, row = (lane>>4)*4 + reg
  const int cc = lane & 15;
  const int cr = (lane >> 4) * 4;
#pragma unroll
  for (int mi = 0; mi < MR; ++mi) {
    const int rowb = m0 + wm * (BM / 2) + mi * 16 + cr;
#pragma unroll
    for (int j = 0; j < 4; ++j) {
      const int col = n0 + wn * 64 + j * 16 + cc;
#pragma unroll
      for (int r = 0; r < 4; ++r) {
        const int  row  = rowb + r;
        const long loff = (long)row * N + col;
        const long off  = (long)z * sC + loff;
        const float v   = acc[mi][j][r];
        if (MODE == 0) {
          Cb[off] = __float2bfloat16(v + biasz[col]);
        } else if (MODE == 1) {
          float sc = v * (1.0f / 32.0f) + pos_bias[loff];
          if (mask[off] == 0) sc = -1e9f;
          Cb[off] = __float2bfloat16(__expf(fminf(sc, 60.0f)));   // E, unnormalized
        } else if (MODE == 2) {
          Cb[off] = __float2bfloat16(v * inv_sum[z * S_ + row]);
        } else {
          Cf[off] = v + biasz[col] + xres[off];
        }
      }
    }
  }
}

// -------- transpose v[b] (S x H) -> vT[b] (H x S), bf16, 64x64 LDS tiles --------
__global__ void transpose_kernel(const bf16* __restrict__ v, bf16* __restrict__ vT) {
  __shared__ bf16 tile[64][65];
  const int b     = blockIdx.z;
  const int sBase = blockIdx.x * 64;
  const int hBase = blockIdx.y * 64;
  const bf16* vb  = v  + (long)b * SH;
  bf16*       vTb = vT + (long)b * SH;
  const int tx = threadIdx.x & 63;
  const int ty = threadIdx.x >> 6;
#pragma unroll
  for (int r = ty; r < 64; r += 4)
    tile[r][tx] = vb[(long)(sBase + r) * H_ + hBase + tx];
  __syncthreads();
#pragma unroll
  for (int r = ty; r < 64; r += 4)
    vTb[(long)(hBase + r) * S_ + sBase + tx] = tile[tx][r];
}

// -------- rownorm: sum E row (bf16), write inv_sum + normalized fp32 attn -------
__global__ void rownorm_kernel(const bf16* __restrict__ E, float* __restrict__ attn_f,
                               float* __restrict__ inv_sum) {
  const long row = blockIdx.x;            // B*S rows
  const int  tid = threadIdx.x;
  const uint4 d = *(const uint4*)(E + row * (long)S_ + tid * 8);
  float ev[8];
  ev[0] = __uint_as_float(d.x << 16); ev[1] = __uint_as_float(d.x & 0xffff0000u);
  ev[2] = __uint_as_float(d.y << 16); ev[3] = __uint_as_float(d.y & 0xffff0000u);
  ev[4] = __uint_as_float(d.z << 16); ev[5] = __uint_as_float(d.z & 0xffff0000u);
  ev[6] = __uint_as_float(d.w << 16); ev[7] = __uint_as_float(d.w & 0xffff0000u);
  float s = 0.f;
#pragma unroll
  for (int i = 0; i < 8; ++i) s += ev[i];
  s = wave_reduce_sum(s);
  __shared__ float red[4];
  if ((tid & 63) == 0) red[tid >> 6] = s;
  __syncthreads();
  const float inv = 1.0f / fmaxf(red[0] + red[1] + red[2] + red[3], 1e-30f);
  if (tid == 0) inv_sum[row] = inv;
  float4 o0, o1;
  o0.x = bf16r(ev[0] * inv); o0.y = bf16r(ev[1] * inv);
  o0.z = bf16r(ev[2] * inv); o0.w = bf16r(ev[3] * inv);
  o1.x = bf16r(ev[4] * inv); o1.y = bf16r(ev[5] * inv);
  o1.z = bf16r(ev[6] * inv); o1.w = bf16r(ev[7] * inv);
  float4* dst = (float4*)(attn_f + row * (long)S_ + tid * 8);
  dst[0] = o0;
  dst[1] = o1;
}

// -------- layernorm over H=1024, fp32 in-place (row-local) ----------------------
__global__ void ln_kernel(float* __restrict__ h, const float* __restrict__ gamma,
                          const float* __restrict__ beta) {
  const long row = blockIdx.x;            // B*S rows
  float* hr = h + row * (long)H_;
  const int tid = threadIdx.x;
  float v[4];
  float s = 0.f;
#pragma unroll
  for (int i = 0; i < 4; ++i) { v[i] = hr[tid + i * 256]; s += v[i]; }
  s = wave_reduce_sum(s);
  __shared__ float redA[4], redB[4];
  if ((tid & 63) == 0) redA[tid >> 6] = s;
  __syncthreads();
  const float mu = (redA[0] + redA[1] + redA[2] + redA[3]) * (1.0f / H_);
  float vs = 0.f;
#pragma unroll
  for (int i = 0; i < 4; ++i) { const float d = v[i] - mu; vs += d * d; }
  vs = wave_reduce_sum(vs);
  if ((tid & 63) == 0) redB[tid >> 6] = vs;
  __syncthreads();
  const float var  = (redB[0] + redB[1] + redB[2] + redB[3]) * (1.0f / H_);
  const float rstd = rsqrtf(var + 1e-5f);
#pragma unroll
  for (int i = 0; i < 4; ++i) {
    const int c = tid + i * 256;
    hr[c] = bf16r((v[i] - mu) * rstd * gamma[c] + beta[c]);
  }
}

extern "C" void kernel_launch(void* const* d_in, const int* in_sizes, int n_in,
                              void* d_out, int out_size, void* d_ws, size_t ws_size,
                              hipStream_t stream) {
  const float* x        = (const float*)d_in[0];
  const int*   mask     = (const int*)d_in[1];
  const float* Wq       = (const float*)d_in[2];
  const float* bq       = (const float*)d_in[3];
  const float* Wk       = (const float*)d_in[4];
  const float* bk       = (const float*)d_in[5];
  const float* Wv       = (const float*)d_in[6];
  const float* bv       = (const float*)d_in[7];
  const float* pos_bias = (const float*)d_in[8];
  const float* Wo       = (const float*)d_in[9];
  const float* bo       = (const float*)d_in[10];
  const float* gamma    = (const float*)d_in[11];
  const float* beta     = (const float*)d_in[12];

  // fp32 outputs: normed [0,32MiB), attn [32,96MiB)
  float* normed_f = (float*)d_out;
  float* attn_f   = (float*)((char*)d_out + ((size_t)32 << 20));

  const size_t MiB = (size_t)1 << 20;
  bf16*  xpb     = (bf16*)d_ws;                            // [  0, 16)
  bf16*  q_b     = (bf16*)((char*)d_ws +  16 * MiB);       // [ 16, 32)
  bf16*  kbuf    = (bf16*)((char*)d_ws +  32 * MiB);       // [ 32, 48)
  bf16*  vbuf    = (bf16*)((char*)d_ws +  48 * MiB);       // [ 48, 64)
  bf16*  vT      = (bf16*)((char*)d_ws +  64 * MiB);       // [ 64, 80)
  bf16*  ctx     = (bf16*)((char*)d_ws +  80 * MiB);       // [ 80, 96)
  bf16*  attn_b  = (bf16*)((char*)d_ws +  96 * MiB);       // [ 96,128) E (unnorm)
  bf16*  wts     = (bf16*)((char*)d_ws + 128 * MiB);       // [128,136)
  float* inv_sum = (float*)((char*)d_ws + 136 * MiB);      // 32 KB
  bf16* Wqb = wts, *Wob = wts + 3 * HH;

  const int MQKV = B_ * S_;   // 8192

  // 1) prep: weights->bf16 (4096 blocks) + xpb = bf16(x+pe) (16384 blocks)
  prep_kernel<<<dim3(20480), 256, 0, stream>>>(Wq, Wk, Wv, Wo, wts, x, xpb);

  // 2) q,k,v projections; grid 32x4x3 = 384 blocks (256-sq tile)
  gemm_nt<0, 256><<<dim3(32, 4, 3), 512, 0, stream>>>(xpb, 0, Wqb, HH, q_b, nullptr, BSH,
                                                      MQKV, H_, H_, bq, bk, bv,
                                                      nullptr, nullptr, nullptr, nullptr);

  // 3) vT[b] = v[b]^T
  transpose_kernel<<<dim3(S_ / 64, H_ / 64, B_), 256, 0, stream>>>(vbuf, vT);

  // 4) E = exp(q*k^T/32 + pos_bias, masked) -> bf16   grid 8x8x4 = 256 blocks
  gemm_nt<1, 256><<<dim3(8, 8, 4), 512, 0, stream>>>(q_b, SH, kbuf, SH,
                                                     attn_b, nullptr, SS,
                                                     S_, S_, H_, nullptr, nullptr, nullptr,
                                                     pos_bias, mask, nullptr, nullptr);

  // 5) rownorm: inv_sum + normalized fp32 attn output
  rownorm_kernel<<<B_ * S_, 256, 0, stream>>>(attn_b, attn_f, inv_sum);

  // 6) ctx = (E @ v) * inv_sum   grid 16x4x4 = 256 blocks (128x256 tile)
  gemm_nt<2, 128><<<dim3(16, 4, 4), 512, 0, stream>>>(attn_b, SS, vT, SH,
                                                      ctx, nullptr, SH,
                                                      S_, H_, S_, nullptr, nullptr, nullptr,
                                                      nullptr, nullptr, nullptr, inv_sum);

  // 7) h = ctx * Wo^T + bo + x   grid 64x4 = 256 blocks (128x256 tile)
  gemm_nt<3, 128><<<dim3(64, 4, 1), 512, 0, stream>>>(ctx, 0, Wob, 0, nullptr, normed_f, 0,
                                                      MQKV, H_, H_, bo, nullptr, nullptr,
                                                      nullptr, nullptr, x, nullptr);

  // 8) layernorm in-place (row-local)
  ln_kernel<<<B_ * S_, 256, 0, stream>>>(normed_f, gamma, beta);
}

// Round 6
// 433.218 us; speedup vs baseline: 1.1712x; 1.1712x over previous
//
#include <hip/hip_runtime.h>
#include <hip/hip_bf16.h>
#include <math.h>

typedef __hip_bfloat16 bf16;
typedef __bf16 bf16x8 __attribute__((ext_vector_type(8)));
typedef float f32x4 __attribute__((ext_vector_type(4)));

static constexpr int  B_  = 4, S_ = 2048, H_ = 1024;
static constexpr long BSH = (long)B_ * S_ * H_;   // 8,388,608
static constexpr long SH  = (long)S_ * H_;        // 2,097,152
static constexpr long SS  = (long)S_ * S_;        // 4,194,304
static constexpr long HH  = (long)H_ * H_;        // 1,048,576

// async global->LDS, 16B per lane; LDS dest is wave-uniform base + lane*16
#define GLOAD_LDS16(gp, lp)                                                          \
  __builtin_amdgcn_global_load_lds((__attribute__((address_space(1))) void*)(gp),    \
                                   (__attribute__((address_space(3))) void*)(lp),    \
                                   16, 0, 0)

__device__ __forceinline__ float wave_reduce_sum(float v) {
#pragma unroll
  for (int o = 32; o; o >>= 1) v += __shfl_xor(v, o, 64);
  return v;
}
__device__ __forceinline__ float bf16r(float v) {
  return __bfloat162float(__float2bfloat16(v));
}

// -------- prep: weights fp32->bf16 (blocks 0..4095) + PE-add (4096..20479)
//          + mask bit-pack (20480..22527)
__global__ void prep_kernel(const float* __restrict__ Wq, const float* __restrict__ Wk,
                            const float* __restrict__ Wv, const float* __restrict__ Wo,
                            bf16* __restrict__ wdst,
                            const float* __restrict__ x, bf16* __restrict__ xpb,
                            const int* __restrict__ mask, unsigned* __restrict__ mask_bits) {
  const int bx  = blockIdx.x;
  const int tid = threadIdx.x;
  if (bx < 4096) {                       // ---- weight conversion, H*H/4 per weight
    const int w = bx >> 10;
    const float* src = (w == 0) ? Wq : (w == 1) ? Wk : (w == 2) ? Wv : Wo;
    bf16* d = wdst + (long)w * HH;
    const int idx = ((bx & 1023) << 8) + tid;
    const float4 f = ((const float4*)src)[idx];
    d[idx * 4 + 0] = __float2bfloat16(f.x);
    d[idx * 4 + 1] = __float2bfloat16(f.y);
    d[idx * 4 + 2] = __float2bfloat16(f.z);
    d[idx * 4 + 3] = __float2bfloat16(f.w);
  } else if (bx < 20480) {               // ---- xpb = bf16(x + pe), pair-indexed
    const long idx = (((long)(bx - 4096)) << 8) + tid;     // over B*S*(H/2)
    const int  i   = (int)(idx & (H_ / 2 - 1));
    const long bs  = idx >> 9;
    const int  s   = (int)(bs & (S_ - 1));
    const float div = __expf((float)(2 * i) * (-9.210340371976184f / (float)H_));
    const float ang = (float)s * div;
    const float2 xv = ((const float2*)x)[idx];
    xpb[idx * 2 + 0] = __float2bfloat16(xv.x + __sinf(ang));
    xpb[idx * 2 + 1] = __float2bfloat16(xv.y + __cosf(ang));
  } else {                               // ---- mask -> 1 bit/elem (B*S*S/32 words)
    const long uidx = (((long)(bx - 20480)) << 8) + tid;   // word index
    const int4* mp  = (const int4*)mask + uidx * 8;        // 32 ints = 128B/thread
    unsigned bits = 0;
#pragma unroll
    for (int q = 0; q < 8; ++q) {
      const int4 v = mp[q];
      bits |= (v.x ? 1u : 0u) << (q * 4 + 0);
      bits |= (v.y ? 1u : 0u) << (q * 4 + 1);
      bits |= (v.z ? 1u : 0u) << (q * 4 + 2);
      bits |= (v.w ? 1u : 0u) << (q * 4 + 3);
    }
    mask_bits[uidx] = bits;
  }
}

// -------- NT GEMM, 128x128 tile, BK=64, 256 thr (2x2 waves, 4x4 MFMA each) ------
// r0's verified 2-barrier structure (stage-all -> syncthreads -> compute ->
// syncthreads), single LDS buffer, 32 KB.  BK=64 halves the per-K drain count
// vs r0 (16 iters instead of 32 at K=1024).  Read-side k-slot XOR (row&7)
// swizzle with the inverse permutation applied to the GLOBAL staging source;
// gload_lds dest stays linear (rule 21; mechanism verified in round 2).
// C[M,N] = A[M,K] * B[N,K]^T, A/B bf16 K-contiguous packed (ld == K).
// blockIdx.z = batch; A += z*sA, B += z*sB, C offset z*sC.
// MODE 0: Cb = bf16(acc + biasz[col])                       (QKV, z picks bias)
// MODE 1: Cb = bf16(exp(clamp(acc/32 + pos_bias, maskbit))) (unnormalized E)
// MODE 2: Cb = bf16(acc * inv_sum[z*S+row])                 (context, normalized)
// MODE 3: Cf = acc + bias0[col] + xres[m,n]          (fp32) (out proj + residual)
template <int MODE>
__global__ void gemm_nt(const bf16* __restrict__ A, long sA,
                        const bf16* __restrict__ Bm, long sB,
                        bf16* __restrict__ Cb, float* __restrict__ Cf, long sC,
                        int M, int N, int K,
                        const float* __restrict__ bias0,
                        const float* __restrict__ bias1,
                        const float* __restrict__ bias2,
                        const float* __restrict__ pos_bias,
                        const unsigned* __restrict__ mask_bits,
                        const float* __restrict__ xres,
                        const float* __restrict__ inv_sum) {
  constexpr int BM = 128, BN = 128, BK = 64;
  __shared__ bf16 As[BM * BK];   // 16 KB
  __shared__ bf16 Bs[BN * BK];   // 16 KB

  const int tid  = threadIdx.x;
  const int lane = tid & 63;
  const int wave = tid >> 6;
  const int wm   = wave & 1;
  const int wn   = wave >> 1;
  const int z    = blockIdx.z;
  const int m0   = blockIdx.x * BM;
  const int n0   = blockIdx.y * BN;

  const bf16* Ab = A  + (long)z * sA;
  const bf16* Bb = Bm + (long)z * sB;

  // staging: per matrix 1024 slots of 8 bf16; thread t covers slots t+256q.
  // slot s -> row s>>3, LDS 16B-pos p = s&7; GLOBAL colslot = p ^ (row&7)
  // (inverse of the read swizzle; row&7 invariant under row+32).
  const int rw = tid >> 3;                   // base row (rows rw+32q)
  const int cp = (tid & 7) ^ (rw & 7);       // permuted global 16B-colslot
  const bf16* ga = Ab + (long)(m0 + rw) * K + cp * 8;
  const bf16* gb = Bb + (long)(n0 + rw) * K + cp * 8;
  bf16* la = As + tid * 8;
  bf16* lb = Bs + tid * 8;

  f32x4 acc[4][4] = {};

  const int fr     = lane & 15;              // row within 16-frag
  const int k0slot = lane >> 4;              // k 16B-slot base (0..3)
  const int sw     = fr & 7;                 // read-side XOR key (rows 16-aligned)

  for (int k0 = 0; k0 < K; k0 += BK) {
#pragma unroll
    for (int q = 0; q < 4; ++q) {
      GLOAD_LDS16(ga + (long)(32 * q) * K + k0, la + q * 2048);
      GLOAD_LDS16(gb + (long)(32 * q) * K + k0, lb + q * 2048);
    }
    __syncthreads();   // drains vmcnt -> tile visible
#pragma unroll
    for (int ks = 0; ks < 2; ++ks) {         // two K=32 substeps of the BK=64 tile
      const int co = ((k0slot + 4 * ks) ^ sw) << 4;   // swizzled byte offset in row
      bf16x8 af[4], bfv[4];
#pragma unroll
      for (int i = 0; i < 4; ++i) {
        af[i]  = *(const bf16x8*)((const char*)As + (wm * 64 + i * 16 + fr) * 128 + co);
        bfv[i] = *(const bf16x8*)((const char*)Bs + (wn * 64 + i * 16 + fr) * 128 + co);
      }
#pragma unroll
      for (int i = 0; i < 4; ++i)
#pragma unroll
        for (int j = 0; j < 4; ++j)
          acc[i][j] = __builtin_amdgcn_mfma_f32_16x16x32_bf16(af[i], bfv[j], acc[i][j], 0, 0, 0);
    }
    __syncthreads();   // all waves done reading before next overwrite
  }

  const float* biasz = (MODE == 0) ? ((z == 0) ? bias0 : (z == 1) ? bias1 : bias2) : bias0;

  // C/D layout (verified m89/m91): col = lane&15, row = (lane>>4)*4 + reg
  const int cc = lane & 15;
  const int cr = (lane >> 4) * 4;
#pragma unroll
  for (int i = 0; i < 4; ++i) {
    const int rowb = m0 + wm * 64 + i * 16 + cr;
#pragma unroll
    for (int j = 0; j < 4; ++j) {
      const int col = n0 + wn * 64 + j * 16 + cc;
#pragma unroll
      for (int r = 0; r < 4; ++r) {
        const int  row  = rowb + r;
        const long loff = (long)row * N + col;
        const long off  = (long)z * sC + loff;
        const float v   = acc[i][j][r];
        if (MODE == 0) {
          Cb[off] = __float2bfloat16(v + biasz[col]);
        } else if (MODE == 1) {
          const unsigned mw = mask_bits[off >> 5];
          float sc = v * (1.0f / 32.0f) + pos_bias[loff];
          if (((mw >> (col & 31)) & 1u) == 0u) sc = -1e9f;
          Cb[off] = __float2bfloat16(__expf(fminf(sc, 60.0f)));   // E, unnormalized
        } else if (MODE == 2) {
          Cb[off] = __float2bfloat16(v * inv_sum[z * S_ + row]);
        } else {
          Cf[off] = v + biasz[col] + xres[off];
        }
      }
    }
  }
}

// -------- transpose v[b] (S x H) -> vT[b] (H x S), bf16, 64x64 LDS tiles --------
__global__ void transpose_kernel(const bf16* __restrict__ v, bf16* __restrict__ vT) {
  __shared__ bf16 tile[64][65];
  const int b     = blockIdx.z;
  const int sBase = blockIdx.x * 64;
  const int hBase = blockIdx.y * 64;
  const bf16* vb  = v  + (long)b * SH;
  bf16*       vTb = vT + (long)b * SH;
  const int tx = threadIdx.x & 63;
  const int ty = threadIdx.x >> 6;
#pragma unroll
  for (int r = ty; r < 64; r += 4)
    tile[r][tx] = vb[(long)(sBase + r) * H_ + hBase + tx];
  __syncthreads();
#pragma unroll
  for (int r = ty; r < 64; r += 4)
    vTb[(long)(hBase + r) * S_ + sBase + tx] = tile[tx][r];
}

// -------- rownorm: sum E row (bf16), write inv_sum + normalized fp32 attn -------
__global__ void rownorm_kernel(const bf16* __restrict__ E, float* __restrict__ attn_f,
                               float* __restrict__ inv_sum) {
  const long row = blockIdx.x;            // B*S rows
  const int  tid = threadIdx.x;
  // load 8 contiguous bf16 (16 B) per thread
  const uint4 d = *(const uint4*)(E + row * (long)S_ + tid * 8);
  float ev[8];
  ev[0] = __uint_as_float(d.x << 16); ev[1] = __uint_as_float(d.x & 0xffff0000u);
  ev[2] = __uint_as_float(d.y << 16); ev[3] = __uint_as_float(d.y & 0xffff0000u);
  ev[4] = __uint_as_float(d.z << 16); ev[5] = __uint_as_float(d.z & 0xffff0000u);
  ev[6] = __uint_as_float(d.w << 16); ev[7] = __uint_as_float(d.w & 0xffff0000u);
  float s = 0.f;
#pragma unroll
  for (int i = 0; i < 8; ++i) s += ev[i];
  s = wave_reduce_sum(s);
  __shared__ float red[4];
  if ((tid & 63) == 0) red[tid >> 6] = s;
  __syncthreads();
  const float inv = 1.0f / fmaxf(red[0] + red[1] + red[2] + red[3], 1e-30f);
  if (tid == 0) inv_sum[row] = inv;
  float4 o0, o1;
  o0.x = bf16r(ev[0] * inv); o0.y = bf16r(ev[1] * inv);
  o0.z = bf16r(ev[2] * inv); o0.w = bf16r(ev[3] * inv);
  o1.x = bf16r(ev[4] * inv); o1.y = bf16r(ev[5] * inv);
  o1.z = bf16r(ev[6] * inv); o1.w = bf16r(ev[7] * inv);
  float4* dst = (float4*)(attn_f + row * (long)S_ + tid * 8);
  dst[0] = o0;
  dst[1] = o1;
}

// -------- layernorm over H=1024, fp32 in-place (row-local) ----------------------
__global__ void ln_kernel(float* __restrict__ h, const float* __restrict__ gamma,
                          const float* __restrict__ beta) {
  const long row = blockIdx.x;            // B*S rows
  float* hr = h + row * (long)H_;
  const int tid = threadIdx.x;
  float v[4];
  float s = 0.f;
#pragma unroll
  for (int i = 0; i < 4; ++i) { v[i] = hr[tid + i * 256]; s += v[i]; }
  s = wave_reduce_sum(s);
  __shared__ float redA[4], redB[4];
  if ((tid & 63) == 0) redA[tid >> 6] = s;
  __syncthreads();
  const float mu = (redA[0] + redA[1] + redA[2] + redA[3]) * (1.0f / H_);
  float vs = 0.f;
#pragma unroll
  for (int i = 0; i < 4; ++i) { const float d = v[i] - mu; vs += d * d; }
  vs = wave_reduce_sum(vs);
  if ((tid & 63) == 0) redB[tid >> 6] = vs;
  __syncthreads();
  const float var  = (redB[0] + redB[1] + redB[2] + redB[3]) * (1.0f / H_);
  const float rstd = rsqrtf(var + 1e-5f);
#pragma unroll
  for (int i = 0; i < 4; ++i) {
    const int c = tid + i * 256;
    hr[c] = bf16r((v[i] - mu) * rstd * gamma[c] + beta[c]);
  }
}

extern "C" void kernel_launch(void* const* d_in, const int* in_sizes, int n_in,
                              void* d_out, int out_size, void* d_ws, size_t ws_size,
                              hipStream_t stream) {
  const float* x        = (const float*)d_in[0];
  const int*   mask     = (const int*)d_in[1];
  const float* Wq       = (const float*)d_in[2];
  const float* bq       = (const float*)d_in[3];
  const float* Wk       = (const float*)d_in[4];
  const float* bk       = (const float*)d_in[5];
  const float* Wv       = (const float*)d_in[6];
  const float* bv       = (const float*)d_in[7];
  const float* pos_bias = (const float*)d_in[8];
  const float* Wo       = (const float*)d_in[9];
  const float* bo       = (const float*)d_in[10];
  const float* gamma    = (const float*)d_in[11];
  const float* beta     = (const float*)d_in[12];

  // fp32 outputs: normed [0,32MiB), attn [32,96MiB)
  float* normed_f = (float*)d_out;
  float* attn_f   = (float*)((char*)d_out + ((size_t)32 << 20));

  // d_ws layout (~139.1 MiB used)
  const size_t MiB = (size_t)1 << 20;
  bf16*     xpb       = (bf16*)d_ws;                          // [  0, 16)
  bf16*     q_b       = (bf16*)((char*)d_ws +  16 * MiB);     // [ 16, 32)
  bf16*     kbuf      = (bf16*)((char*)d_ws +  32 * MiB);     // [ 32, 48)
  bf16*     vbuf      = (bf16*)((char*)d_ws +  48 * MiB);     // [ 48, 64)
  bf16*     vT        = (bf16*)((char*)d_ws +  64 * MiB);     // [ 64, 80)
  bf16*     ctx       = (bf16*)((char*)d_ws +  80 * MiB);     // [ 80, 96)
  bf16*     attn_b    = (bf16*)((char*)d_ws +  96 * MiB);     // [ 96,128) E (unnorm)
  bf16*     wts       = (bf16*)((char*)d_ws + 128 * MiB);     // [128,136)
  float*    inv_sum   = (float*)((char*)d_ws + 136 * MiB);    // 32 KB
  unsigned* mask_bits = (unsigned*)((char*)d_ws + 137 * MiB); // 2 MiB
  bf16* Wqb = wts, *Wob = wts + 3 * HH;

  const int MQKV = B_ * S_;   // 8192

  // 1) prep: weights->bf16 (4096) + xpb = bf16(x+pe) (16384) + mask bits (2048)
  prep_kernel<<<dim3(22528), 256, 0, stream>>>(Wq, Wk, Wv, Wo, wts, x, xpb,
                                               mask, mask_bits);

  // 2) q,k,v projections in ONE launch (z selects W, bias, output slice)
  gemm_nt<0><<<dim3(64, 8, 3), 256, 0, stream>>>(xpb, 0, Wqb, HH, q_b, nullptr, BSH,
                                                 MQKV, H_, H_, bq, bk, bv,
                                                 nullptr, nullptr, nullptr, nullptr);

  // 3) vT[b] = v[b]^T
  transpose_kernel<<<dim3(S_ / 64, H_ / 64, B_), 256, 0, stream>>>(vbuf, vT);

  // 4) E = exp(q*k^T/32 + pos_bias, masked) -> bf16 (unnormalized attention)
  gemm_nt<1><<<dim3(16, 16, B_), 256, 0, stream>>>(q_b, SH, kbuf, SH,
                                                   attn_b, nullptr, SS,
                                                   S_, S_, H_, nullptr, nullptr, nullptr,
                                                   pos_bias, mask_bits, nullptr, nullptr);

  // 5) rownorm: inv_sum + normalized fp32 attn output
  rownorm_kernel<<<B_ * S_, 256, 0, stream>>>(attn_b, attn_f, inv_sum);

  // 6) ctx = (E @ v) * inv_sum  (all batches)
  gemm_nt<2><<<dim3(16, 8, B_), 256, 0, stream>>>(attn_b, SS, vT, SH,
                                                  ctx, nullptr, SH,
                                                  S_, H_, S_, nullptr, nullptr, nullptr,
                                                  nullptr, nullptr, nullptr, inv_sum);

  // 7) h = ctx * Wo^T + bo + x (fp32 into normed region)
  gemm_nt<3><<<dim3(64, 8, 1), 256, 0, stream>>>(ctx, 0, Wob, 0, nullptr, normed_f, 0,
                                                 MQKV, H_, H_, bo, nullptr, nullptr,
                                                 nullptr, nullptr, x, nullptr);

  // 8) layernorm in-place (row-local)
  ln_kernel<<<B_ * S_, 256, 0, stream>>>(normed_f, gamma, beta);
}

// Round 7
// 430.318 us; speedup vs baseline: 1.1791x; 1.0067x over previous
//
#include <hip/hip_runtime.h>
#include <hip/hip_bf16.h>
#include <math.h>

typedef __hip_bfloat16 bf16;
typedef __bf16 bf16x8 __attribute__((ext_vector_type(8)));
typedef float f32x4 __attribute__((ext_vector_type(4)));

static constexpr int  B_  = 4, S_ = 2048, H_ = 1024;
static constexpr long BSH = (long)B_ * S_ * H_;   // 8,388,608
static constexpr long SH  = (long)S_ * H_;        // 2,097,152
static constexpr long SS  = (long)S_ * S_;        // 4,194,304
static constexpr long HH  = (long)H_ * H_;        // 1,048,576

// async global->LDS, 16B per lane; LDS dest is wave-uniform base + lane*16
#define GLOAD_LDS16(gp, lp)                                                          \
  __builtin_amdgcn_global_load_lds((__attribute__((address_space(1))) void*)(gp),    \
                                   (__attribute__((address_space(3))) void*)(lp),    \
                                   16, 0, 0)

// raw barrier (does NOT drain vmcnt) + compiler memory fence
#define BARRIER() do { __builtin_amdgcn_s_barrier(); asm volatile("" ::: "memory"); } while (0)

template <int N> __device__ __forceinline__ void waitcnt_vm() {
  if constexpr (N == 0)      asm volatile("s_waitcnt vmcnt(0)" ::: "memory");
  else if constexpr (N == 8) asm volatile("s_waitcnt vmcnt(8)" ::: "memory");
}

__device__ __forceinline__ float wave_reduce_sum(float v) {
#pragma unroll
  for (int o = 32; o; o >>= 1) v += __shfl_xor(v, o, 64);
  return v;
}
__device__ __forceinline__ float bf16r(float v) {
  return __bfloat162float(__float2bfloat16(v));
}

// -------- prep: weights fp32->bf16 (blocks 0..4095) + PE-add (4096..20479)
//          + mask bit-pack (20480..22527)
__global__ void prep_kernel(const float* __restrict__ Wq, const float* __restrict__ Wk,
                            const float* __restrict__ Wv, const float* __restrict__ Wo,
                            bf16* __restrict__ wdst,
                            const float* __restrict__ x, bf16* __restrict__ xpb,
                            const int* __restrict__ mask, unsigned* __restrict__ mask_bits) {
  const int bx  = blockIdx.x;
  const int tid = threadIdx.x;
  if (bx < 4096) {                       // ---- weight conversion, H*H/4 per weight
    const int w = bx >> 10;
    const float* src = (w == 0) ? Wq : (w == 1) ? Wk : (w == 2) ? Wv : Wo;
    bf16* d = wdst + (long)w * HH;
    const int idx = ((bx & 1023) << 8) + tid;
    const float4 f = ((const float4*)src)[idx];
    d[idx * 4 + 0] = __float2bfloat16(f.x);
    d[idx * 4 + 1] = __float2bfloat16(f.y);
    d[idx * 4 + 2] = __float2bfloat16(f.z);
    d[idx * 4 + 3] = __float2bfloat16(f.w);
  } else if (bx < 20480) {               // ---- xpb = bf16(x + pe), pair-indexed
    const long idx = (((long)(bx - 4096)) << 8) + tid;     // over B*S*(H/2)
    const int  i   = (int)(idx & (H_ / 2 - 1));
    const long bs  = idx >> 9;
    const int  s   = (int)(bs & (S_ - 1));
    const float div = __expf((float)(2 * i) * (-9.210340371976184f / (float)H_));
    const float ang = (float)s * div;
    const float2 xv = ((const float2*)x)[idx];
    xpb[idx * 2 + 0] = __float2bfloat16(xv.x + __sinf(ang));
    xpb[idx * 2 + 1] = __float2bfloat16(xv.y + __cosf(ang));
  } else {                               // ---- mask -> 1 bit/elem (B*S*S/32 words)
    const long uidx = (((long)(bx - 20480)) << 8) + tid;   // word index
    const int4* mp  = (const int4*)mask + uidx * 8;        // 32 ints = 128B/thread
    unsigned bits = 0;
#pragma unroll
    for (int q = 0; q < 8; ++q) {
      const int4 v = mp[q];
      bits |= (v.x ? 1u : 0u) << (q * 4 + 0);
      bits |= (v.y ? 1u : 0u) << (q * 4 + 1);
      bits |= (v.z ? 1u : 0u) << (q * 4 + 2);
      bits |= (v.w ? 1u : 0u) << (q * 4 + 3);
    }
    mask_bits[uidx] = bits;
  }
}

// -------- NT GEMM, 128x128 tile, BK=64, 256 thr (2x2 waves, 4x4 MFMA each) ------
// r6's verified winner + double-buffer with COUNTED vmcnt (minimal T4 delta):
//   iter kt: stage(kt+1 -> buf^1) [8 loads]; s_waitcnt vmcnt(8) (tile kt landed,
//   next tile stays in flight); s_barrier; compute(buf); s_barrier.
// Ledger: barrier#1 after per-wave vmcnt => tile kt globally visible; barrier#2
// at iter end => all waves done reading buf before iter kt+1 overwrites it.
// Read-side k-slot XOR (row&7) swizzle, inverse permutation on the GLOBAL
// staging source, linear gload_lds dest (rule 21; conflicts measured 0).
// C[M,N] = A[M,K] * B[N,K]^T, A/B bf16 K-contiguous packed (ld == K).
// MODE 0: Cb = bf16(acc + biasz[col])                       (QKV, z picks bias)
// MODE 1: Cb = bf16(exp(clamp(acc/32 + pos_bias, maskbit))) (unnormalized E)
// MODE 2: Cb = bf16(acc * inv_sum[z*S+row])                 (context, normalized)
// MODE 3: Cf = acc + bias0[col] + xres[m,n]          (fp32) (out proj + residual)
template <int MODE>
__global__ void gemm_nt(const bf16* __restrict__ A, long sA,
                        const bf16* __restrict__ Bm, long sB,
                        bf16* __restrict__ Cb, float* __restrict__ Cf, long sC,
                        int M, int N, int K,
                        const float* __restrict__ bias0,
                        const float* __restrict__ bias1,
                        const float* __restrict__ bias2,
                        const float* __restrict__ pos_bias,
                        const unsigned* __restrict__ mask_bits,
                        const float* __restrict__ xres,
                        const float* __restrict__ inv_sum) {
  constexpr int BM = 128, BN = 128, BK = 64;
  __shared__ bf16 As[2][BM * BK];   // 2 x 16 KB
  __shared__ bf16 Bs[2][BN * BK];   // 2 x 16 KB

  const int tid  = threadIdx.x;
  const int lane = tid & 63;
  const int wave = tid >> 6;
  const int wm   = wave & 1;
  const int wn   = wave >> 1;
  const int z    = blockIdx.z;
  const int m0   = blockIdx.x * BM;
  const int n0   = blockIdx.y * BN;

  const bf16* Ab = A  + (long)z * sA;
  const bf16* Bb = Bm + (long)z * sB;

  // staging: per matrix 1024 slots of 8 bf16; thread t covers slots t+256q.
  // slot s -> row s>>3, LDS 16B-pos p = s&7; GLOBAL colslot = p ^ (row&7)
  // (inverse of the read swizzle; row&7 invariant under row+32).
  const int rw = tid >> 3;                   // base row (rows rw+32q)
  const int cp = (tid & 7) ^ (rw & 7);       // permuted global 16B-colslot
  const bf16* ga = Ab + (long)(m0 + rw) * K + cp * 8;
  const bf16* gb = Bb + (long)(n0 + rw) * K + cp * 8;

  auto stage = [&](int tile, int buf) {
    const long k0 = (long)tile * BK;
#pragma unroll
    for (int q = 0; q < 4; ++q) {
      GLOAD_LDS16(ga + (long)(32 * q) * K + k0, &As[buf][tid * 8 + q * 2048]);
      GLOAD_LDS16(gb + (long)(32 * q) * K + k0, &Bs[buf][tid * 8 + q * 2048]);
    }
  };

  f32x4 acc[4][4] = {};

  const int fr     = lane & 15;              // row within 16-frag
  const int k0slot = lane >> 4;              // k 16B-slot base (0..3)
  const int sw     = fr & 7;                 // read-side XOR key (rows 16-aligned)

  const int nkt = K / BK;                    // 16 or 32
  stage(0, 0);
  for (int kt = 0; kt < nkt; ++kt) {
    const int cur = kt & 1;
    if (kt + 1 < nkt) {
      stage(kt + 1, cur ^ 1);                // issue next tile into other buffer
      waitcnt_vm<8>();                       // tile kt landed; kt+1 stays in flight
    } else {
      waitcnt_vm<0>();
    }
    BARRIER();                               // tile kt visible to all waves
    const char* bAc = (const char*)&As[cur][0];
    const char* bBc = (const char*)&Bs[cur][0];
#pragma unroll
    for (int ks = 0; ks < 2; ++ks) {         // two K=32 substeps of the BK=64 tile
      const int co = ((k0slot + 4 * ks) ^ sw) << 4;   // swizzled byte offset in row
      bf16x8 af[4], bfv[4];
#pragma unroll
      for (int i = 0; i < 4; ++i) {
        af[i]  = *(const bf16x8*)(bAc + (wm * 64 + i * 16 + fr) * 128 + co);
        bfv[i] = *(const bf16x8*)(bBc + (wn * 64 + i * 16 + fr) * 128 + co);
      }
#pragma unroll
      for (int i = 0; i < 4; ++i)
#pragma unroll
        for (int j = 0; j < 4; ++j)
          acc[i][j] = __builtin_amdgcn_mfma_f32_16x16x32_bf16(af[i], bfv[j], acc[i][j], 0, 0, 0);
    }
    BARRIER();                               // all waves done reading buf 'cur'
  }

  const float* biasz = (MODE == 0) ? ((z == 0) ? bias0 : (z == 1) ? bias1 : bias2) : bias0;

  // C/D layout (verified m89/m91): col = lane&15, row = (lane>>4)*4 + reg
  const int cc = lane & 15;
  const int cr = (lane >> 4) * 4;
#pragma unroll
  for (int i = 0; i < 4; ++i) {
    const int rowb = m0 + wm * 64 + i * 16 + cr;
#pragma unroll
    for (int j = 0; j < 4; ++j) {
      const int col = n0 + wn * 64 + j * 16 + cc;
#pragma unroll
      for (int r = 0; r < 4; ++r) {
        const int  row  = rowb + r;
        const long loff = (long)row * N + col;
        const long off  = (long)z * sC + loff;
        const float v   = acc[i][j][r];
        if (MODE == 0) {
          Cb[off] = __float2bfloat16(v + biasz[col]);
        } else if (MODE == 1) {
          const unsigned mw = mask_bits[off >> 5];
          float sc = v * (1.0f / 32.0f) + pos_bias[loff];
          if (((mw >> (col & 31)) & 1u) == 0u) sc = -1e9f;
          Cb[off] = __float2bfloat16(__expf(fminf(sc, 60.0f)));   // E, unnormalized
        } else if (MODE == 2) {
          Cb[off] = __float2bfloat16(v * inv_sum[z * S_ + row]);
        } else {
          Cf[off] = v + biasz[col] + xres[off];
        }
      }
    }
  }
}

// -------- transpose v[b] (S x H) -> vT[b] (H x S), bf16, 64x64 LDS tiles --------
__global__ void transpose_kernel(const bf16* __restrict__ v, bf16* __restrict__ vT) {
  __shared__ bf16 tile[64][65];
  const int b     = blockIdx.z;
  const int sBase = blockIdx.x * 64;
  const int hBase = blockIdx.y * 64;
  const bf16* vb  = v  + (long)b * SH;
  bf16*       vTb = vT + (long)b * SH;
  const int tx = threadIdx.x & 63;
  const int ty = threadIdx.x >> 6;
#pragma unroll
  for (int r = ty; r < 64; r += 4)
    tile[r][tx] = vb[(long)(sBase + r) * H_ + hBase + tx];
  __syncthreads();
#pragma unroll
  for (int r = ty; r < 64; r += 4)
    vTb[(long)(hBase + r) * S_ + sBase + tx] = tile[tx][r];
}

// -------- rownorm: sum E row (bf16), write inv_sum + normalized fp32 attn -------
__global__ void rownorm_kernel(const bf16* __restrict__ E, float* __restrict__ attn_f,
                               float* __restrict__ inv_sum) {
  const long row = blockIdx.x;            // B*S rows
  const int  tid = threadIdx.x;
  // load 8 contiguous bf16 (16 B) per thread
  const uint4 d = *(const uint4*)(E + row * (long)S_ + tid * 8);
  float ev[8];
  ev[0] = __uint_as_float(d.x << 16); ev[1] = __uint_as_float(d.x & 0xffff0000u);
  ev[2] = __uint_as_float(d.y << 16); ev[3] = __uint_as_float(d.y & 0xffff0000u);
  ev[4] = __uint_as_float(d.z << 16); ev[5] = __uint_as_float(d.z & 0xffff0000u);
  ev[6] = __uint_as_float(d.w << 16); ev[7] = __uint_as_float(d.w & 0xffff0000u);
  float s = 0.f;
#pragma unroll
  for (int i = 0; i < 8; ++i) s += ev[i];
  s = wave_reduce_sum(s);
  __shared__ float red[4];
  if ((tid & 63) == 0) red[tid >> 6] = s;
  __syncthreads();
  const float inv = 1.0f / fmaxf(red[0] + red[1] + red[2] + red[3], 1e-30f);
  if (tid == 0) inv_sum[row] = inv;
  float4 o0, o1;
  o0.x = bf16r(ev[0] * inv); o0.y = bf16r(ev[1] * inv);
  o0.z = bf16r(ev[2] * inv); o0.w = bf16r(ev[3] * inv);
  o1.x = bf16r(ev[4] * inv); o1.y = bf16r(ev[5] * inv);
  o1.z = bf16r(ev[6] * inv); o1.w = bf16r(ev[7] * inv);
  float4* dst = (float4*)(attn_f + row * (long)S_ + tid * 8);
  dst[0] = o0;
  dst[1] = o1;
}

// -------- layernorm over H=1024, fp32 in-place (row-local) ----------------------
__global__ void ln_kernel(float* __restrict__ h, const float* __restrict__ gamma,
                          const float* __restrict__ beta) {
  const long row = blockIdx.x;            // B*S rows
  float* hr = h + row * (long)H_;
  const int tid = threadIdx.x;
  float v[4];
  float s = 0.f;
#pragma unroll
  for (int i = 0; i < 4; ++i) { v[i] = hr[tid + i * 256]; s += v[i]; }
  s = wave_reduce_sum(s);
  __shared__ float redA[4], redB[4];
  if ((tid & 63) == 0) redA[tid >> 6] = s;
  __syncthreads();
  const float mu = (redA[0] + redA[1] + redA[2] + redA[3]) * (1.0f / H_);
  float vs = 0.f;
#pragma unroll
  for (int i = 0; i < 4; ++i) { const float d = v[i] - mu; vs += d * d; }
  vs = wave_reduce_sum(vs);
  if ((tid & 63) == 0) redB[tid >> 6] = vs;
  __syncthreads();
  const float var  = (redB[0] + redB[1] + redB[2] + redB[3]) * (1.0f / H_);
  const float rstd = rsqrtf(var + 1e-5f);
#pragma unroll
  for (int i = 0; i < 4; ++i) {
    const int c = tid + i * 256;
    hr[c] = bf16r((v[i] - mu) * rstd * gamma[c] + beta[c]);
  }
}

extern "C" void kernel_launch(void* const* d_in, const int* in_sizes, int n_in,
                              void* d_out, int out_size, void* d_ws, size_t ws_size,
                              hipStream_t stream) {
  const float* x        = (const float*)d_in[0];
  const int*   mask     = (const int*)d_in[1];
  const float* Wq       = (const float*)d_in[2];
  const float* bq       = (const float*)d_in[3];
  const float* Wk       = (const float*)d_in[4];
  const float* bk       = (const float*)d_in[5];
  const float* Wv       = (const float*)d_in[6];
  const float* bv       = (const float*)d_in[7];
  const float* pos_bias = (const float*)d_in[8];
  const float* Wo       = (const float*)d_in[9];
  const float* bo       = (const float*)d_in[10];
  const float* gamma    = (const float*)d_in[11];
  const float* beta     = (const float*)d_in[12];

  // fp32 outputs: normed [0,32MiB), attn [32,96MiB)
  float* normed_f = (float*)d_out;
  float* attn_f   = (float*)((char*)d_out + ((size_t)32 << 20));

  // d_ws layout (~139.1 MiB used)
  const size_t MiB = (size_t)1 << 20;
  bf16*     xpb       = (bf16*)d_ws;                          // [  0, 16)
  bf16*     q_b       = (bf16*)((char*)d_ws +  16 * MiB);     // [ 16, 32)
  bf16*     kbuf      = (bf16*)((char*)d_ws +  32 * MiB);     // [ 32, 48)
  bf16*     vbuf      = (bf16*)((char*)d_ws +  48 * MiB);     // [ 48, 64)
  bf16*     vT        = (bf16*)((char*)d_ws +  64 * MiB);     // [ 64, 80)
  bf16*     ctx       = (bf16*)((char*)d_ws +  80 * MiB);     // [ 80, 96)
  bf16*     attn_b    = (bf16*)((char*)d_ws +  96 * MiB);     // [ 96,128) E (unnorm)
  bf16*     wts       = (bf16*)((char*)d_ws + 128 * MiB);     // [128,136)
  float*    inv_sum   = (float*)((char*)d_ws + 136 * MiB);    // 32 KB
  unsigned* mask_bits = (unsigned*)((char*)d_ws + 137 * MiB); // 2 MiB
  bf16* Wqb = wts, *Wob = wts + 3 * HH;

  const int MQKV = B_ * S_;   // 8192

  // 1) prep: weights->bf16 (4096) + xpb = bf16(x+pe) (16384) + mask bits (2048)
  prep_kernel<<<dim3(22528), 256, 0, stream>>>(Wq, Wk, Wv, Wo, wts, x, xpb,
                                               mask, mask_bits);

  // 2) q,k,v projections in ONE launch (z selects W, bias, output slice)
  gemm_nt<0><<<dim3(64, 8, 3), 256, 0, stream>>>(xpb, 0, Wqb, HH, q_b, nullptr, BSH,
                                                 MQKV, H_, H_, bq, bk, bv,
                                                 nullptr, nullptr, nullptr, nullptr);

  // 3) vT[b] = v[b]^T
  transpose_kernel<<<dim3(S_ / 64, H_ / 64, B_), 256, 0, stream>>>(vbuf, vT);

  // 4) E = exp(q*k^T/32 + pos_bias, masked) -> bf16 (unnormalized attention)
  gemm_nt<1><<<dim3(16, 16, B_), 256, 0, stream>>>(q_b, SH, kbuf, SH,
                                                   attn_b, nullptr, SS,
                                                   S_, S_, H_, nullptr, nullptr, nullptr,
                                                   pos_bias, mask_bits, nullptr, nullptr);

  // 5) rownorm: inv_sum + normalized fp32 attn output
  rownorm_kernel<<<B_ * S_, 256, 0, stream>>>(attn_b, attn_f, inv_sum);

  // 6) ctx = (E @ v) * inv_sum  (all batches)
  gemm_nt<2><<<dim3(16, 8, B_), 256, 0, stream>>>(attn_b, SS, vT, SH,
                                                  ctx, nullptr, SH,
                                                  S_, H_, S_, nullptr, nullptr, nullptr,
                                                  nullptr, nullptr, nullptr, inv_sum);

  // 7) h = ctx * Wo^T + bo + x (fp32 into normed region)
  gemm_nt<3><<<dim3(64, 8, 1), 256, 0, stream>>>(ctx, 0, Wob, 0, nullptr, normed_f, 0,
                                                 MQKV, H_, H_, bo, nullptr, nullptr,
                                                 nullptr, nullptr, x, nullptr);

  // 8) layernorm in-place (row-local)
  ln_kernel<<<B_ * S_, 256, 0, stream>>>(normed_f, gamma, beta);
}

// Round 8
// 419.781 us; speedup vs baseline: 1.2087x; 1.0251x over previous
//
#include <hip/hip_runtime.h>
#include <hip/hip_bf16.h>
#include <math.h>

typedef __hip_bfloat16 bf16;
typedef __bf16 bf16x8 __attribute__((ext_vector_type(8)));
typedef float f32x4 __attribute__((ext_vector_type(4)));

static constexpr int  B_  = 4, S_ = 2048, H_ = 1024;
static constexpr long BSH = (long)B_ * S_ * H_;   // 8,388,608
static constexpr long SH  = (long)S_ * H_;        // 2,097,152
static constexpr long SS  = (long)S_ * S_;        // 4,194,304
static constexpr long HH  = (long)H_ * H_;        // 1,048,576

// async global->LDS, 16B per lane; LDS dest is wave-uniform base + lane*16
#define GLOAD_LDS16(gp, lp)                                                          \
  __builtin_amdgcn_global_load_lds((__attribute__((address_space(1))) void*)(gp),    \
                                   (__attribute__((address_space(3))) void*)(lp),    \
                                   16, 0, 0)

// raw barrier (does NOT drain vmcnt) + compiler memory fence
#define BARRIER() do { __builtin_amdgcn_s_barrier(); asm volatile("" ::: "memory"); } while (0)

template <int N> __device__ __forceinline__ void waitcnt_vm() {
  if constexpr (N == 0)      asm volatile("s_waitcnt vmcnt(0)" ::: "memory");
  else if constexpr (N == 8) asm volatile("s_waitcnt vmcnt(8)" ::: "memory");
}

__device__ __forceinline__ float wave_reduce_sum(float v) {
#pragma unroll
  for (int o = 32; o; o >>= 1) v += __shfl_xor(v, o, 64);
  return v;
}
__device__ __forceinline__ float bf16r(float v) {
  return __bfloat162float(__float2bfloat16(v));
}

// -------- prep: weights fp32->bf16 (blocks 0..4095) + PE-add (4096..20479)
//          + mask bit-pack (20480..22527)
__global__ void prep_kernel(const float* __restrict__ Wq, const float* __restrict__ Wk,
                            const float* __restrict__ Wv, const float* __restrict__ Wo,
                            bf16* __restrict__ wdst,
                            const float* __restrict__ x, bf16* __restrict__ xpb,
                            const int* __restrict__ mask, unsigned* __restrict__ mask_bits) {
  const int bx  = blockIdx.x;
  const int tid = threadIdx.x;
  if (bx < 4096) {                       // ---- weight conversion, H*H/4 per weight
    const int w = bx >> 10;
    const float* src = (w == 0) ? Wq : (w == 1) ? Wk : (w == 2) ? Wv : Wo;
    bf16* d = wdst + (long)w * HH;
    const int idx = ((bx & 1023) << 8) + tid;
    const float4 f = ((const float4*)src)[idx];
    d[idx * 4 + 0] = __float2bfloat16(f.x);
    d[idx * 4 + 1] = __float2bfloat16(f.y);
    d[idx * 4 + 2] = __float2bfloat16(f.z);
    d[idx * 4 + 3] = __float2bfloat16(f.w);
  } else if (bx < 20480) {               // ---- xpb = bf16(x + pe), pair-indexed
    const long idx = (((long)(bx - 4096)) << 8) + tid;     // over B*S*(H/2)
    const int  i   = (int)(idx & (H_ / 2 - 1));
    const long bs  = idx >> 9;
    const int  s   = (int)(bs & (S_ - 1));
    const float div = __expf((float)(2 * i) * (-9.210340371976184f / (float)H_));
    const float ang = (float)s * div;
    const float2 xv = ((const float2*)x)[idx];
    xpb[idx * 2 + 0] = __float2bfloat16(xv.x + __sinf(ang));
    xpb[idx * 2 + 1] = __float2bfloat16(xv.y + __cosf(ang));
  } else {                               // ---- mask -> 1 bit/elem (B*S*S/32 words)
    const long uidx = (((long)(bx - 20480)) << 8) + tid;   // word index
    const int4* mp  = (const int4*)mask + uidx * 8;        // 32 ints = 128B/thread
    unsigned bits = 0;
#pragma unroll
    for (int q = 0; q < 8; ++q) {
      const int4 v = mp[q];
      bits |= (v.x ? 1u : 0u) << (q * 4 + 0);
      bits |= (v.y ? 1u : 0u) << (q * 4 + 1);
      bits |= (v.z ? 1u : 0u) << (q * 4 + 2);
      bits |= (v.w ? 1u : 0u) << (q * 4 + 3);
    }
    mask_bits[uidx] = bits;
  }
}

// -------- NT GEMM, 128x128 tile, BK=64, 256 thr (2x2 waves, 4x4 MFMA each) ------
// Per-mode structure knob (r6 vs r7 measured split):
//   DBUF=false: r6 single 32KB buffer, stage -> syncthreads(drain) -> compute ->
//               syncthreads.  ~2.75 blocks/CU.  Best for short-K modes (0,3).
//   DBUF=true : r7 64KB double-buffer, stage(kt+1) -> s_waitcnt vmcnt(8) ->
//               s_barrier -> compute -> s_barrier.  Counted vmcnt keeps the next
//               tile in flight across the barrier.  Best for modes 1,2.
// Read-side k-slot XOR (row&7) swizzle, inverse permutation on the GLOBAL
// staging source, linear gload_lds dest (rule 21; conflicts measured 0).
// C[M,N] = A[M,K] * B[N,K]^T, A/B bf16 K-contiguous packed (ld == K).
// MODE 0: Cb = bf16(acc + biasz[col])                       (QKV, z picks bias)
// MODE 1: Cb = bf16(exp(clamp(acc/32 + pos_bias, maskbit))) (unnormalized E)
// MODE 2: Cb = bf16(acc * inv_sum[z*S+row])                 (context, normalized)
// MODE 3: Cf = acc + bias0[col] + xres[m,n]          (fp32) (out proj + residual)
template <int MODE, bool DBUF>
__global__ void gemm_nt(const bf16* __restrict__ A, long sA,
                        const bf16* __restrict__ Bm, long sB,
                        bf16* __restrict__ Cb, float* __restrict__ Cf, long sC,
                        int M, int N, int K,
                        const float* __restrict__ bias0,
                        const float* __restrict__ bias1,
                        const float* __restrict__ bias2,
                        const float* __restrict__ pos_bias,
                        const unsigned* __restrict__ mask_bits,
                        const float* __restrict__ xres,
                        const float* __restrict__ inv_sum) {
  constexpr int BM = 128, BN = 128, BK = 64;
  constexpr int NBUF = DBUF ? 2 : 1;
  __shared__ bf16 As[NBUF][BM * BK];   // NBUF x 16 KB
  __shared__ bf16 Bs[NBUF][BN * BK];   // NBUF x 16 KB

  const int tid  = threadIdx.x;
  const int lane = tid & 63;
  const int wave = tid >> 6;
  const int wm   = wave & 1;
  const int wn   = wave >> 1;
  const int z    = blockIdx.z;
  const int m0   = blockIdx.x * BM;
  const int n0   = blockIdx.y * BN;

  const bf16* Ab = A  + (long)z * sA;
  const bf16* Bb = Bm + (long)z * sB;

  // staging: per matrix 1024 slots of 8 bf16; thread t covers slots t+256q.
  // slot s -> row s>>3, LDS 16B-pos p = s&3..7; GLOBAL colslot = p ^ (row&7)
  // (inverse of the read swizzle; row&7 invariant under row+32).
  const int rw = tid >> 3;                   // base row (rows rw+32q)
  const int cp = (tid & 7) ^ (rw & 7);       // permuted global 16B-colslot
  const bf16* ga = Ab + (long)(m0 + rw) * K + cp * 8;
  const bf16* gb = Bb + (long)(n0 + rw) * K + cp * 8;

  auto stage = [&](int tile, int buf) {
    const long k0 = (long)tile * BK;
#pragma unroll
    for (int q = 0; q < 4; ++q) {
      GLOAD_LDS16(ga + (long)(32 * q) * K + k0, &As[buf][tid * 8 + q * 2048]);
      GLOAD_LDS16(gb + (long)(32 * q) * K + k0, &Bs[buf][tid * 8 + q * 2048]);
    }
  };

  f32x4 acc[4][4] = {};

  const int fr     = lane & 15;              // row within 16-frag
  const int k0slot = lane >> 4;              // k 16B-slot base (0..3)
  const int sw     = fr & 7;                 // read-side XOR key (rows 16-aligned)

  auto tile_compute = [&](const char* bAc, const char* bBc) {
#pragma unroll
    for (int ks = 0; ks < 2; ++ks) {         // two K=32 substeps of the BK=64 tile
      const int co = ((k0slot + 4 * ks) ^ sw) << 4;   // swizzled byte offset in row
      bf16x8 af[4], bfv[4];
#pragma unroll
      for (int i = 0; i < 4; ++i) {
        af[i]  = *(const bf16x8*)(bAc + (wm * 64 + i * 16 + fr) * 128 + co);
        bfv[i] = *(const bf16x8*)(bBc + (wn * 64 + i * 16 + fr) * 128 + co);
      }
#pragma unroll
      for (int i = 0; i < 4; ++i)
#pragma unroll
        for (int j = 0; j < 4; ++j)
          acc[i][j] = __builtin_amdgcn_mfma_f32_16x16x32_bf16(af[i], bfv[j], acc[i][j], 0, 0, 0);
    }
  };

  const int nkt = K / BK;                    // 16 or 32
  if constexpr (DBUF) {
    stage(0, 0);
    for (int kt = 0; kt < nkt; ++kt) {
      const int cur = kt & 1;
      if (kt + 1 < nkt) {
        stage(kt + 1, (cur ^ 1) & (NBUF - 1));   // next tile into other buffer
        waitcnt_vm<8>();                     // tile kt landed; kt+1 stays in flight
      } else {
        waitcnt_vm<0>();
      }
      BARRIER();                             // tile kt visible to all waves
      tile_compute((const char*)&As[cur][0], (const char*)&Bs[cur][0]);
      BARRIER();                             // all waves done reading buf 'cur'
    }
  } else {
    for (int kt = 0; kt < nkt; ++kt) {
      stage(kt, 0);
      __syncthreads();                       // drains vmcnt -> tile visible
      tile_compute((const char*)&As[0][0], (const char*)&Bs[0][0]);
      __syncthreads();                       // all waves done before overwrite
    }
  }

  const float* biasz = (MODE == 0) ? ((z == 0) ? bias0 : (z == 1) ? bias1 : bias2) : bias0;

  // C/D layout (verified m89/m91): col = lane&15, row = (lane>>4)*4 + reg
  const int cc = lane & 15;
  const int cr = (lane >> 4) * 4;
#pragma unroll
  for (int i = 0; i < 4; ++i) {
    const int rowb = m0 + wm * 64 + i * 16 + cr;
#pragma unroll
    for (int j = 0; j < 4; ++j) {
      const int col = n0 + wn * 64 + j * 16 + cc;
#pragma unroll
      for (int r = 0; r < 4; ++r) {
        const int  row  = rowb + r;
        const long loff = (long)row * N + col;
        const long off  = (long)z * sC + loff;
        const float v   = acc[i][j][r];
        if (MODE == 0) {
          Cb[off] = __float2bfloat16(v + biasz[col]);
        } else if (MODE == 1) {
          const unsigned mw = mask_bits[off >> 5];
          float sc = v * (1.0f / 32.0f) + pos_bias[loff];
          if (((mw >> (col & 31)) & 1u) == 0u) sc = -1e9f;
          Cb[off] = __float2bfloat16(__expf(fminf(sc, 60.0f)));   // E, unnormalized
        } else if (MODE == 2) {
          Cb[off] = __float2bfloat16(v * inv_sum[z * S_ + row]);
        } else {
          Cf[off] = v + biasz[col] + xres[off];
        }
      }
    }
  }
}

// -------- transpose v[b] (S x H) -> vT[b] (H x S), bf16, 64x64 LDS tiles --------
__global__ void transpose_kernel(const bf16* __restrict__ v, bf16* __restrict__ vT) {
  __shared__ bf16 tile[64][65];
  const int b     = blockIdx.z;
  const int sBase = blockIdx.x * 64;
  const int hBase = blockIdx.y * 64;
  const bf16* vb  = v  + (long)b * SH;
  bf16*       vTb = vT + (long)b * SH;
  const int tx = threadIdx.x & 63;
  const int ty = threadIdx.x >> 6;
#pragma unroll
  for (int r = ty; r < 64; r += 4)
    tile[r][tx] = vb[(long)(sBase + r) * H_ + hBase + tx];
  __syncthreads();
#pragma unroll
  for (int r = ty; r < 64; r += 4)
    vTb[(long)(hBase + r) * S_ + sBase + tx] = tile[tx][r];
}

// -------- rownorm: sum E row (bf16), write inv_sum + normalized fp32 attn -------
__global__ void rownorm_kernel(const bf16* __restrict__ E, float* __restrict__ attn_f,
                               float* __restrict__ inv_sum) {
  const long row = blockIdx.x;            // B*S rows
  const int  tid = threadIdx.x;
  // load 8 contiguous bf16 (16 B) per thread
  const uint4 d = *(const uint4*)(E + row * (long)S_ + tid * 8);
  float ev[8];
  ev[0] = __uint_as_float(d.x << 16); ev[1] = __uint_as_float(d.x & 0xffff0000u);
  ev[2] = __uint_as_float(d.y << 16); ev[3] = __uint_as_float(d.y & 0xffff0000u);
  ev[4] = __uint_as_float(d.z << 16); ev[5] = __uint_as_float(d.z & 0xffff0000u);
  ev[6] = __uint_as_float(d.w << 16); ev[7] = __uint_as_float(d.w & 0xffff0000u);
  float s = 0.f;
#pragma unroll
  for (int i = 0; i < 8; ++i) s += ev[i];
  s = wave_reduce_sum(s);
  __shared__ float red[4];
  if ((tid & 63) == 0) red[tid >> 6] = s;
  __syncthreads();
  const float inv = 1.0f / fmaxf(red[0] + red[1] + red[2] + red[3], 1e-30f);
  if (tid == 0) inv_sum[row] = inv;
  float4 o0, o1;
  o0.x = bf16r(ev[0] * inv); o0.y = bf16r(ev[1] * inv);
  o0.z = bf16r(ev[2] * inv); o0.w = bf16r(ev[3] * inv);
  o1.x = bf16r(ev[4] * inv); o1.y = bf16r(ev[5] * inv);
  o1.z = bf16r(ev[6] * inv); o1.w = bf16r(ev[7] * inv);
  float4* dst = (float4*)(attn_f + row * (long)S_ + tid * 8);
  dst[0] = o0;
  dst[1] = o1;
}

// -------- layernorm over H=1024, fp32 in-place (row-local) ----------------------
__global__ void ln_kernel(float* __restrict__ h, const float* __restrict__ gamma,
                          const float* __restrict__ beta) {
  const long row = blockIdx.x;            // B*S rows
  float* hr = h + row * (long)H_;
  const int tid = threadIdx.x;
  float v[4];
  float s = 0.f;
#pragma unroll
  for (int i = 0; i < 4; ++i) { v[i] = hr[tid + i * 256]; s += v[i]; }
  s = wave_reduce_sum(s);
  __shared__ float redA[4], redB[4];
  if ((tid & 63) == 0) redA[tid >> 6] = s;
  __syncthreads();
  const float mu = (redA[0] + redA[1] + redA[2] + redA[3]) * (1.0f / H_);
  float vs = 0.f;
#pragma unroll
  for (int i = 0; i < 4; ++i) { const float d = v[i] - mu; vs += d * d; }
  vs = wave_reduce_sum(vs);
  if ((tid & 63) == 0) redB[tid >> 6] = vs;
  __syncthreads();
  const float var  = (redB[0] + redB[1] + redB[2] + redB[3]) * (1.0f / H_);
  const float rstd = rsqrtf(var + 1e-5f);
#pragma unroll
  for (int i = 0; i < 4; ++i) {
    const int c = tid + i * 256;
    hr[c] = bf16r((v[i] - mu) * rstd * gamma[c] + beta[c]);
  }
}

extern "C" void kernel_launch(void* const* d_in, const int* in_sizes, int n_in,
                              void* d_out, int out_size, void* d_ws, size_t ws_size,
                              hipStream_t stream) {
  const float* x        = (const float*)d_in[0];
  const int*   mask     = (const int*)d_in[1];
  const float* Wq       = (const float*)d_in[2];
  const float* bq       = (const float*)d_in[3];
  const float* Wk       = (const float*)d_in[4];
  const float* bk       = (const float*)d_in[5];
  const float* Wv       = (const float*)d_in[6];
  const float* bv       = (const float*)d_in[7];
  const float* pos_bias = (const float*)d_in[8];
  const float* Wo       = (const float*)d_in[9];
  const float* bo       = (const float*)d_in[10];
  const float* gamma    = (const float*)d_in[11];
  const float* beta     = (const float*)d_in[12];

  // fp32 outputs: normed [0,32MiB), attn [32,96MiB)
  float* normed_f = (float*)d_out;
  float* attn_f   = (float*)((char*)d_out + ((size_t)32 << 20));

  // d_ws layout (~139.1 MiB used)
  const size_t MiB = (size_t)1 << 20;
  bf16*     xpb       = (bf16*)d_ws;                          // [  0, 16)
  bf16*     q_b       = (bf16*)((char*)d_ws +  16 * MiB);     // [ 16, 32)
  bf16*     kbuf      = (bf16*)((char*)d_ws +  32 * MiB);     // [ 32, 48)
  bf16*     vbuf      = (bf16*)((char*)d_ws +  48 * MiB);     // [ 48, 64)
  bf16*     vT        = (bf16*)((char*)d_ws +  64 * MiB);     // [ 64, 80)
  bf16*     ctx       = (bf16*)((char*)d_ws +  80 * MiB);     // [ 80, 96)
  bf16*     attn_b    = (bf16*)((char*)d_ws +  96 * MiB);     // [ 96,128) E (unnorm)
  bf16*     wts       = (bf16*)((char*)d_ws + 128 * MiB);     // [128,136)
  float*    inv_sum   = (float*)((char*)d_ws + 136 * MiB);    // 32 KB
  unsigned* mask_bits = (unsigned*)((char*)d_ws + 137 * MiB); // 2 MiB
  bf16* Wqb = wts, *Wob = wts + 3 * HH;

  const int MQKV = B_ * S_;   // 8192

  // 1) prep: weights->bf16 (4096) + xpb = bf16(x+pe) (16384) + mask bits (2048)
  prep_kernel<<<dim3(22528), 256, 0, stream>>>(Wq, Wk, Wv, Wo, wts, x, xpb,
                                               mask, mask_bits);

  // 2) q,k,v projections in ONE launch (z selects W, bias, output slice)
  //    single-buffer (r6 config — measured faster for this mode)
  gemm_nt<0, false><<<dim3(64, 8, 3), 256, 0, stream>>>(xpb, 0, Wqb, HH, q_b, nullptr, BSH,
                                                        MQKV, H_, H_, bq, bk, bv,
                                                        nullptr, nullptr, nullptr, nullptr);

  // 3) vT[b] = v[b]^T
  transpose_kernel<<<dim3(S_ / 64, H_ / 64, B_), 256, 0, stream>>>(vbuf, vT);

  // 4) E = exp(q*k^T/32 + pos_bias, masked) -> bf16 (dbuf counted-vmcnt)
  gemm_nt<1, true><<<dim3(16, 16, B_), 256, 0, stream>>>(q_b, SH, kbuf, SH,
                                                         attn_b, nullptr, SS,
                                                         S_, S_, H_, nullptr, nullptr, nullptr,
                                                         pos_bias, mask_bits, nullptr, nullptr);

  // 5) rownorm: inv_sum + normalized fp32 attn output
  rownorm_kernel<<<B_ * S_, 256, 0, stream>>>(attn_b, attn_f, inv_sum);

  // 6) ctx = (E @ v) * inv_sum  (K=2048, longest loop — dbuf counted-vmcnt)
  gemm_nt<2, true><<<dim3(16, 8, B_), 256, 0, stream>>>(attn_b, SS, vT, SH,
                                                        ctx, nullptr, SH,
                                                        S_, H_, S_, nullptr, nullptr, nullptr,
                                                        nullptr, nullptr, nullptr, inv_sum);

  // 7) h = ctx * Wo^T + bo + x (single-buffer, structurally == MODE 0)
  gemm_nt<3, false><<<dim3(64, 8, 1), 256, 0, stream>>>(ctx, 0, Wob, 0, nullptr, normed_f, 0,
                                                        MQKV, H_, H_, bo, nullptr, nullptr,
                                                        nullptr, nullptr, x, nullptr);

  // 8) layernorm in-place (row-local)
  ln_kernel<<<B_ * S_, 256, 0, stream>>>(normed_f, gamma, beta);
}